// Round 2
// baseline (127.702 us; speedup 1.0000x reference)
//
#include <hip/hip_runtime.h>
#include <hip/hip_cooperative_groups.h>

namespace cg = cooperative_groups;

#define BB 2
#define CC 64
#define CI 32
#define NPIX 9216   // 96*96
#define TN 128      // pixels per block tile (phase 1 and phase 4)
#define NCH 72      // NPIX / TN chunks per batch
#define NBLK (BB * NCH)  // 144 blocks

struct P1 { float tile[16][68]; };
struct P3 {
  float S[CC][CC + 1];
  float Gt[CC][CI + 1];   // gw transposed
  float r[CC];
  float A[CI][CC + 1];    // pw @ S
  float M[CI][CI + 1];
  float T1[CI][CC + 1];   // (M^T tw)
  float u[CI], v[CI], t2[CI];
};
struct P4 { float Wt[CC][68]; float xt[CC][TN]; float bl[CC]; };

#define SMEM_BYTES (sizeof(P4) > sizeof(P3) ? sizeof(P4) : sizeof(P3))

__global__ __launch_bounds__(256) void fused_nonlocal(
    const float* __restrict__ x, const float* __restrict__ tw,
    const float* __restrict__ tb, const float* __restrict__ pw,
    const float* __restrict__ pb, const float* __restrict__ gw,
    const float* __restrict__ gb, const float* __restrict__ rw,
    const float* __restrict__ rb, float* __restrict__ z,
    float* __restrict__ Spart, float* __restrict__ rpart,
    float* __restrict__ Sf, float* __restrict__ rf,
    float* __restrict__ Wc, float* __restrict__ bc) {
  cg::grid_group grid = cg::this_grid();
  __shared__ __align__(16) char smem[SMEM_BYTES];
  const int t = threadIdx.x;
  const int blk = blockIdx.x;

  // ---------------- phase 1: partial S = X X^T, r = X @ 1 per 128-px tile
  {
    P1& sm = *reinterpret_cast<P1*>(smem);
    const int batch = blk / NCH;
    const int chk = blk - batch * NCH;
    const float* __restrict__ X =
        x + (size_t)batch * CC * NPIX + (size_t)chk * TN;
    const int colL = t & 15;
    const int rowL = t >> 4;
    const int i0 = rowL * 4;
    const int j0 = colL * 4;
    float acc[4][4] = {};
    float racc[4] = {0.f, 0.f, 0.f, 0.f};

    for (int s = 0; s < TN; s += 16) {
#pragma unroll
      for (int j = 0; j < 4; ++j) {
        const int c = rowL + 16 * j;
        const float v = X[(size_t)c * NPIX + s + colL];
        sm.tile[colL][c] = v;
        racc[j] += v;
      }
      __syncthreads();
#pragma unroll
      for (int n = 0; n < 16; ++n) {
        const float4 av = *reinterpret_cast<const float4*>(&sm.tile[n][i0]);
        const float4 bv = *reinterpret_cast<const float4*>(&sm.tile[n][j0]);
        const float a[4] = {av.x, av.y, av.z, av.w};
        const float b[4] = {bv.x, bv.y, bv.z, bv.w};
#pragma unroll
        for (int ii = 0; ii < 4; ++ii)
#pragma unroll
          for (int jj = 0; jj < 4; ++jj) acc[ii][jj] += a[ii] * b[jj];
      }
      __syncthreads();
    }

    float* Sp = Spart + (size_t)blk * (CC * CC);
#pragma unroll
    for (int ii = 0; ii < 4; ++ii) {
      float4 v4 = make_float4(acc[ii][0], acc[ii][1], acc[ii][2], acc[ii][3]);
      *reinterpret_cast<float4*>(&Sp[(i0 + ii) * CC + j0]) = v4;
    }
#pragma unroll
    for (int j = 0; j < 4; ++j) {
      float v = racc[j];
      v += __shfl_down(v, 8, 16);
      v += __shfl_down(v, 4, 16);
      v += __shfl_down(v, 2, 16);
      v += __shfl_down(v, 1, 16);
      if (colL == 0) rpart[(size_t)blk * CC + rowL + 16 * j] = v;
    }
  }
  __threadfence();
  grid.sync();

  // ---------------- phase 2: fold partials (blocks 0..BB*16-1)
  if (blk < BB * 16) {
    const int batch = blk >> 4;
    const int part = blk & 15;
    const int idx = part * 256 + t;
    float s = 0.f;
    for (int k = 0; k < NCH; ++k)
      s += Spart[((size_t)(batch * NCH + k)) * (CC * CC) + idx];
    Sf[batch * (CC * CC) + idx] = s;
    if (part == 0 && t < CC) {
      float rs = 0.f;
      for (int k = 0; k < NCH; ++k)
        rs += rpart[((size_t)(batch * NCH + k)) * CC + t];
      rf[batch * CC + t] = rs;
    }
  }
  __threadfence();
  grid.sync();

  // ---------------- phase 3: tiny algebra -> W_b (64x64), b_b (64), blocks 0..1
  if (blk < BB) {
    P3& sm = *reinterpret_cast<P3*>(smem);
    const int b = blk;

    for (int idx = t; idx < CC * CC; idx += 256)
      sm.S[idx >> 6][idx & 63] = Sf[b * CC * CC + idx];
    for (int idx = t; idx < CI * CC; idx += 256) {
      int c = idx >> 6, j = idx & 63;
      sm.Gt[j][c] = gw[idx];
    }
    if (t < CC) sm.r[t] = rf[b * CC + t];
    __syncthreads();

    if (t < CI) {
      float s = 0.f;
      for (int i = 0; i < CC; ++i) s += gw[t * CC + i] * sm.r[i];
      sm.u[t] = s;
    } else if (t < 2 * CI) {
      const int k = t - CI;
      float s = 0.f;
      for (int i = 0; i < CC; ++i) s += pw[k * CC + i] * sm.r[i];
      sm.v[k] = s;
    }
    // A[k][j] = sum_i pw[k][i] S[i][j]
    for (int o = t; o < CI * CC; o += 256) {
      const int k = o >> 6, j = o & 63;
      float s = 0.f;
      for (int i = 0; i < CC; ++i) s += pw[k * CC + i] * sm.S[i][j];
      sm.A[k][j] = s;
    }
    __syncthreads();

    // M[k][c] = sum_j A[k][j] Gt[j][c] + v[k] gb[c] + pb[k] u[c] + N pb[k] gb[c]
    for (int o = t; o < CI * CI; o += 256) {
      const int k = o >> 5, c = o & 31;
      float s = 0.f;
      for (int j = 0; j < CC; ++j) s += sm.A[k][j] * sm.Gt[j][c];
      s += sm.v[k] * gb[c] + pb[k] * sm.u[c] + (float)NPIX * pb[k] * gb[c];
      sm.M[k][c] = s;
    }
    __syncthreads();

    // T1[c][j] = sum_k M[k][c] tw[k][j];  t2[c] = sum_k M[k][c] tb[k]
    for (int o = t; o < CI * CC; o += 256) {
      const int c = o >> 6, j = o & 63;
      float s = 0.f;
      for (int k = 0; k < CI; ++k) s += sm.M[k][c] * tw[k * CC + j];
      sm.T1[c][j] = s;
    }
    if (t < CI) {
      float s = 0.f;
      for (int k = 0; k < CI; ++k) s += sm.M[k][t] * tb[k];
      sm.t2[t] = s;
    }
    __syncthreads();

    const float invN = 1.0f / (float)NPIX;
    for (int o = t; o < CC * CC; o += 256) {
      const int oc = o >> 6, j = o & 63;
      float s = 0.f;
      for (int c = 0; c < CI; ++c) s += rw[oc * CI + c] * sm.T1[c][j];
      Wc[b * CC * CC + o] = s * invN;
    }
    if (t < CC) {
      float s = 0.f;
      for (int c = 0; c < CI; ++c) s += rw[t * CI + c] * sm.t2[c];
      bc[b * CC + t] = s * invN + rb[t];
    }
  }
  __threadfence();
  grid.sync();

  // ---------------- phase 4: Z = X + W_b X + b_b
  {
    P4& sm = *reinterpret_cast<P4*>(smem);
    const int batch = blk / NCH;
    const int nb = blk - batch * NCH;
    const int n0 = nb * TN;
    const float* __restrict__ X = x + (size_t)batch * CC * NPIX;
    float* __restrict__ Z = z + (size_t)batch * CC * NPIX;
    const float* __restrict__ W = Wc + (size_t)batch * CC * CC;

    for (int idx = t; idx < CC * CC; idx += 256) {
      const int c = idx >> 6, k = idx & 63;
      sm.Wt[k][c] = W[idx];
    }
    for (int idx = t; idx < CC * TN; idx += 256) {
      const int k = idx >> 7, n = idx & (TN - 1);
      sm.xt[k][n] = X[(size_t)k * NPIX + n0 + n];
    }
    if (t < CC) sm.bl[t] = bc[batch * CC + t];
    __syncthreads();

    const int c0 = (t >> 5) * 8;
    const int m0 = (t & 31) * 4;
    float acc[8][4] = {};
#pragma unroll 4
    for (int k = 0; k < CC; ++k) {
      const float4 xv = *reinterpret_cast<const float4*>(&sm.xt[k][m0]);
      const float4 w0 = *reinterpret_cast<const float4*>(&sm.Wt[k][c0]);
      const float4 w1 = *reinterpret_cast<const float4*>(&sm.Wt[k][c0 + 4]);
      const float xa[4] = {xv.x, xv.y, xv.z, xv.w};
      const float wa[8] = {w0.x, w0.y, w0.z, w0.w, w1.x, w1.y, w1.z, w1.w};
#pragma unroll
      for (int cc = 0; cc < 8; ++cc)
#pragma unroll
        for (int nn = 0; nn < 4; ++nn) acc[cc][nn] += wa[cc] * xa[nn];
    }

#pragma unroll
    for (int cc = 0; cc < 8; ++cc) {
      const int c = c0 + cc;
      const float4 xr = *reinterpret_cast<const float4*>(&sm.xt[c][m0]);
      const float bb2 = sm.bl[c];
      float4 o;
      o.x = acc[cc][0] + xr.x + bb2;
      o.y = acc[cc][1] + xr.y + bb2;
      o.z = acc[cc][2] + xr.z + bb2;
      o.w = acc[cc][3] + xr.w + bb2;
      *reinterpret_cast<float4*>(&Z[(size_t)c * NPIX + n0 + m0]) = o;
    }
  }
}

extern "C" void kernel_launch(void* const* d_in, const int* in_sizes, int n_in,
                              void* d_out, int out_size, void* d_ws,
                              size_t ws_size, hipStream_t stream) {
  (void)in_sizes; (void)n_in; (void)out_size; (void)ws_size;
  const float* x  = (const float*)d_in[0];
  const float* tw = (const float*)d_in[1];
  const float* tb = (const float*)d_in[2];
  const float* pw = (const float*)d_in[3];
  const float* pb = (const float*)d_in[4];
  const float* gw = (const float*)d_in[5];
  const float* gb = (const float*)d_in[6];
  const float* rw = (const float*)d_in[7];
  const float* rb = (const float*)d_in[8];
  float* z = (float*)d_out;

  float* Spart = (float*)d_ws;                                   // 144*4096
  float* rpart = Spart + (size_t)NBLK * CC * CC;                 // 144*64
  float* Sf    = rpart + (size_t)NBLK * CC;                      // 2*4096
  float* rf    = Sf + BB * CC * CC;                              // 2*64
  float* Wcb   = rf + BB * CC;                                   // 2*4096
  float* bcb   = Wcb + BB * CC * CC;                             // 2*64

  void* args[] = {&x, &tw, &tb, &pw, &pb, &gw, &gb, &rw, &rb,
                  &z, &Spart, &rpart, &Sf, &rf, &Wcb, &bcb};
  hipLaunchCooperativeKernel((void*)fused_nonlocal, dim3(NBLK), dim3(256),
                             args, 0, stream);
}

// Round 3
// 58.912 us; speedup vs baseline: 2.1677x; 2.1677x over previous
//
#include <hip/hip_runtime.h>

#define BB 2
#define CC 64
#define CI 32
#define NPIX 9216   // 96*96
#define TN 128      // pixels per block tile
#define NCH 72      // NPIX / TN chunks per batch
#define NBLK (BB * NCH)  // 144 blocks

struct Alg {
  float S[CC][CC + 1];
  float Gt[CC][CI + 1];   // gw transposed
  float A[CI][CC + 1];    // pw @ S
  float M[CI][CI + 1];
  float T1[CI][CC + 1];   // (M^T tw)
  float r[CC];
  float u[CI], v[CI], t2[CI];
};

struct Smem {
  union U {
    float tile[16][68];   // phase 1 staging
    Alg alg;              // phase 2 algebra (46.6 KB)
    float xt[CC][TN];     // phase 3 x tile (32.8 KB)
  } u;
  float Wt[CC][68];       // Wt[inch][outch], persists algebra -> apply
  float bl[CC];
};

__global__ __launch_bounds__(256) void fused_nonlocal(
    const float* __restrict__ x, const float* __restrict__ tw,
    const float* __restrict__ tb, const float* __restrict__ pw,
    const float* __restrict__ pb, const float* __restrict__ gw,
    const float* __restrict__ gb, const float* __restrict__ rw,
    const float* __restrict__ rb, float* __restrict__ z,
    float* __restrict__ Sf, float* __restrict__ rf,
    unsigned int* __restrict__ ctr) {
  __shared__ __align__(16) Smem sm;
  const int t = threadIdx.x;
  const int blk = blockIdx.x;
  const int batch = blk / NCH;
  const int chk = blk - batch * NCH;

  // ---------------- phase 1: S += X_chunk X_chunk^T, r += X_chunk @ 1
  {
    const float* __restrict__ X =
        x + (size_t)batch * CC * NPIX + (size_t)chk * TN;
    const int colL = t & 15;
    const int rowL = t >> 4;
    const int i0 = rowL * 4;
    const int j0 = colL * 4;
    float acc[4][4] = {};
    float racc[4] = {0.f, 0.f, 0.f, 0.f};

    for (int s = 0; s < TN; s += 16) {
#pragma unroll
      for (int j = 0; j < 4; ++j) {
        const int c = rowL + 16 * j;
        const float v = X[(size_t)c * NPIX + s + colL];
        sm.u.tile[colL][c] = v;
        racc[j] += v;
      }
      __syncthreads();
#pragma unroll
      for (int n = 0; n < 16; ++n) {
        const float4 av = *reinterpret_cast<const float4*>(&sm.u.tile[n][i0]);
        const float4 bv = *reinterpret_cast<const float4*>(&sm.u.tile[n][j0]);
        const float a[4] = {av.x, av.y, av.z, av.w};
        const float b[4] = {bv.x, bv.y, bv.z, bv.w};
#pragma unroll
        for (int ii = 0; ii < 4; ++ii)
#pragma unroll
          for (int jj = 0; jj < 4; ++jj) acc[ii][jj] += a[ii] * b[jj];
      }
      __syncthreads();
    }

    float* Sb = Sf + (size_t)batch * CC * CC;
#pragma unroll
    for (int ii = 0; ii < 4; ++ii)
#pragma unroll
      for (int jj = 0; jj < 4; ++jj)
        unsafeAtomicAdd(&Sb[(i0 + ii) * CC + j0 + jj], acc[ii][jj]);

#pragma unroll
    for (int j = 0; j < 4; ++j) {
      float v = racc[j];
      v += __shfl_down(v, 8, 16);
      v += __shfl_down(v, 4, 16);
      v += __shfl_down(v, 2, 16);
      v += __shfl_down(v, 1, 16);
      if (colL == 0) unsafeAtomicAdd(&rf[batch * CC + rowL + 16 * j], v);
    }
  }

  // ---------------- light-weight global barrier (release/acquire on ctr)
  __syncthreads();  // drains this block's outstanding atomics (vmcnt)
  if (t == 0) {
    __hip_atomic_fetch_add(ctr, 1u, __ATOMIC_RELEASE,
                           __HIP_MEMORY_SCOPE_AGENT);
    while (__hip_atomic_load(ctr, __ATOMIC_RELAXED,
                             __HIP_MEMORY_SCOPE_AGENT) < (unsigned)NBLK) {
      __builtin_amdgcn_s_sleep(2);
    }
    __threadfence();  // acquire: invalidate stale lines before normal loads
  }
  __syncthreads();

  // ---------------- phase 2: redundant tiny algebra -> Wt, bl in LDS
  {
    Alg& a = sm.u.alg;
    const float* Sb = Sf + (size_t)batch * CC * CC;
    for (int idx = t; idx < CC * CC; idx += 256)
      a.S[idx >> 6][idx & 63] = __hip_atomic_load(
          &Sb[idx], __ATOMIC_RELAXED, __HIP_MEMORY_SCOPE_AGENT);
    for (int idx = t; idx < CI * CC; idx += 256) {
      int c = idx >> 6, j = idx & 63;
      a.Gt[j][c] = gw[idx];
    }
    if (t < CC)
      a.r[t] = __hip_atomic_load(&rf[batch * CC + t], __ATOMIC_RELAXED,
                                 __HIP_MEMORY_SCOPE_AGENT);
    __syncthreads();

    if (t < CI) {
      float s = 0.f;
      for (int i = 0; i < CC; ++i) s += gw[t * CC + i] * a.r[i];
      a.u[t] = s;
    } else if (t < 2 * CI) {
      const int k = t - CI;
      float s = 0.f;
      for (int i = 0; i < CC; ++i) s += pw[k * CC + i] * a.r[i];
      a.v[k] = s;
    }
    // A[k][j] = sum_i pw[k][i] S[i][j]
    for (int o = t; o < CI * CC; o += 256) {
      const int k = o >> 6, j = o & 63;
      float s = 0.f;
      for (int i = 0; i < CC; ++i) s += pw[k * CC + i] * a.S[i][j];
      a.A[k][j] = s;
    }
    __syncthreads();

    // M[k][c] = sum_j A[k][j] Gt[j][c] + v[k] gb[c] + pb[k] u[c] + N pb[k] gb[c]
    for (int o = t; o < CI * CI; o += 256) {
      const int k = o >> 5, c = o & 31;
      float s = 0.f;
      for (int j = 0; j < CC; ++j) s += a.A[k][j] * a.Gt[j][c];
      s += a.v[k] * gb[c] + pb[k] * a.u[c] + (float)NPIX * pb[k] * gb[c];
      a.M[k][c] = s;
    }
    __syncthreads();

    // T1[c][j] = sum_k M[k][c] tw[k][j];  t2[c] = sum_k M[k][c] tb[k]
    for (int o = t; o < CI * CC; o += 256) {
      const int c = o >> 6, j = o & 63;
      float s = 0.f;
      for (int k = 0; k < CI; ++k) s += a.M[k][c] * tw[k * CC + j];
      a.T1[c][j] = s;
    }
    if (t < CI) {
      float s = 0.f;
      for (int k = 0; k < CI; ++k) s += a.M[k][t] * tb[k];
      a.t2[t] = s;
    }
    __syncthreads();

    const float invN = 1.0f / (float)NPIX;
    // Wt[j][oc] = invN * sum_c rw[oc][c] T1[c][j]   (transposed for apply)
    for (int o = t; o < CC * CC; o += 256) {
      const int oc = o >> 6, j = o & 63;
      float s = 0.f;
      for (int c = 0; c < CI; ++c) s += rw[oc * CI + c] * a.T1[c][j];
      sm.Wt[j][oc] = s * invN;
    }
    if (t < CC) {
      float s = 0.f;
      for (int c = 0; c < CI; ++c) s += rw[t * CI + c] * a.t2[c];
      sm.bl[t] = s * invN + rb[t];
    }
  }
  __syncthreads();

  // ---------------- phase 3: Z = X + W_b X + b_b for this block's tile
  {
    const int n0 = chk * TN;
    const float* __restrict__ X = x + (size_t)batch * CC * NPIX;
    float* __restrict__ Z = z + (size_t)batch * CC * NPIX;

    for (int idx = t; idx < CC * TN; idx += 256) {
      const int k = idx >> 7, n = idx & (TN - 1);
      sm.u.xt[k][n] = X[(size_t)k * NPIX + n0 + n];
    }
    __syncthreads();

    const int c0 = (t >> 5) * 8;
    const int m0 = (t & 31) * 4;
    float acc[8][4] = {};
#pragma unroll 4
    for (int k = 0; k < CC; ++k) {
      const float4 xv = *reinterpret_cast<const float4*>(&sm.u.xt[k][m0]);
      const float4 w0 = *reinterpret_cast<const float4*>(&sm.Wt[k][c0]);
      const float4 w1 = *reinterpret_cast<const float4*>(&sm.Wt[k][c0 + 4]);
      const float xa[4] = {xv.x, xv.y, xv.z, xv.w};
      const float wa[8] = {w0.x, w0.y, w0.z, w0.w, w1.x, w1.y, w1.z, w1.w};
#pragma unroll
      for (int cc = 0; cc < 8; ++cc)
#pragma unroll
        for (int nn = 0; nn < 4; ++nn) acc[cc][nn] += wa[cc] * xa[nn];
    }

#pragma unroll
    for (int cc = 0; cc < 8; ++cc) {
      const int c = c0 + cc;
      const float4 xr = *reinterpret_cast<const float4*>(&sm.u.xt[c][m0]);
      const float bb2 = sm.bl[c];
      float4 o;
      o.x = acc[cc][0] + xr.x + bb2;
      o.y = acc[cc][1] + xr.y + bb2;
      o.z = acc[cc][2] + xr.z + bb2;
      o.w = acc[cc][3] + xr.w + bb2;
      *reinterpret_cast<float4*>(&Z[(size_t)c * NPIX + n0 + m0]) = o;
    }
  }
}

extern "C" void kernel_launch(void* const* d_in, const int* in_sizes, int n_in,
                              void* d_out, int out_size, void* d_ws,
                              size_t ws_size, hipStream_t stream) {
  (void)in_sizes; (void)n_in; (void)out_size; (void)ws_size;
  const float* x  = (const float*)d_in[0];
  const float* tw = (const float*)d_in[1];
  const float* tb = (const float*)d_in[2];
  const float* pw = (const float*)d_in[3];
  const float* pb = (const float*)d_in[4];
  const float* gw = (const float*)d_in[5];
  const float* gb = (const float*)d_in[6];
  const float* rw = (const float*)d_in[7];
  const float* rb = (const float*)d_in[8];
  float* z = (float*)d_out;

  float* Sf = (float*)d_ws;                       // BB*4096
  float* rf = Sf + (size_t)BB * CC * CC;          // BB*64
  unsigned int* ctr = (unsigned int*)(rf + BB * CC);

  const size_t zero_bytes = ((size_t)BB * (CC * CC + CC)) * sizeof(float) + 16;
  hipMemsetAsync(d_ws, 0, zero_bytes, stream);

  hipLaunchKernelGGL(fused_nonlocal, dim3(NBLK), dim3(256), 0, stream,
                     x, tw, tb, pw, pb, gw, gb, rw, rb, z, Sf, rf, ctr);
}

// Round 4
// 54.141 us; speedup vs baseline: 2.3587x; 1.0881x over previous
//
#include <hip/hip_runtime.h>

#define BB 2
#define CC 64
#define CI 32
#define NPIX 9216   // 96*96
#define TN 128      // pixels per block tile
#define NCH 72      // NPIX / TN chunks per batch
#define NBLK (BB * NCH)  // 144 blocks

struct Alg {
  float S[CC][CC + 1];
  float Gt[CC][CI + 1];   // gw transposed
  float A[CI][CC + 1];    // pw @ S
  float M[CI][CI + 1];
  float T1[CI][CC + 1];   // (M^T tw)
  float r[CC];
  float u[CI], v[CI], t2[CI];
};

struct Smem {
  union U {
    float tile[16][68];   // phase 1 staging
    Alg alg;              // phase 2 algebra (46.6 KB)
    float xt[CC][TN];     // phase 3 x tile (32.8 KB)
  } u;
  float Wt[CC][68];       // Wt[inch][outch], persists algebra -> apply
  float bl[CC];
};

__global__ __launch_bounds__(256) void fused_nonlocal(
    const float* __restrict__ x, const float* __restrict__ tw,
    const float* __restrict__ tb, const float* __restrict__ pw,
    const float* __restrict__ pb, const float* __restrict__ gw,
    const float* __restrict__ gb, const float* __restrict__ rw,
    const float* __restrict__ rb, float* __restrict__ z,
    float* __restrict__ Sf, float* __restrict__ rf,
    unsigned int* __restrict__ ctr) {
  __shared__ __align__(16) Smem sm;
  const int t = threadIdx.x;
  const int blk = blockIdx.x;
  const int batch = blk / NCH;
  const int chk = blk - batch * NCH;

  // ---------------- phase 1: S += X_chunk X_chunk^T, r += X_chunk @ 1
  {
    const float* __restrict__ X =
        x + (size_t)batch * CC * NPIX + (size_t)chk * TN;
    const int colL = t & 15;
    const int rowL = t >> 4;
    const int i0 = rowL * 4;
    const int j0 = colL * 4;
    float acc[4][4] = {};
    float racc[4] = {0.f, 0.f, 0.f, 0.f};

    for (int s = 0; s < TN; s += 16) {
#pragma unroll
      for (int j = 0; j < 4; ++j) {
        const int c = rowL + 16 * j;
        const float v = X[(size_t)c * NPIX + s + colL];
        sm.u.tile[colL][c] = v;
        racc[j] += v;
      }
      __syncthreads();
#pragma unroll
      for (int n = 0; n < 16; ++n) {
        const float4 av = *reinterpret_cast<const float4*>(&sm.u.tile[n][i0]);
        const float4 bv = *reinterpret_cast<const float4*>(&sm.u.tile[n][j0]);
        const float a[4] = {av.x, av.y, av.z, av.w};
        const float b[4] = {bv.x, bv.y, bv.z, bv.w};
#pragma unroll
        for (int ii = 0; ii < 4; ++ii)
#pragma unroll
          for (int jj = 0; jj < 4; ++jj) acc[ii][jj] += a[ii] * b[jj];
      }
      __syncthreads();
    }

    float* Sb = Sf + (size_t)batch * CC * CC;
#pragma unroll
    for (int ii = 0; ii < 4; ++ii)
#pragma unroll
      for (int jj = 0; jj < 4; ++jj)
        unsafeAtomicAdd(&Sb[(i0 + ii) * CC + j0 + jj], acc[ii][jj]);

#pragma unroll
    for (int j = 0; j < 4; ++j) {
      float v = racc[j];
      v += __shfl_down(v, 8, 16);
      v += __shfl_down(v, 4, 16);
      v += __shfl_down(v, 2, 16);
      v += __shfl_down(v, 1, 16);
      if (colL == 0) unsafeAtomicAdd(&rf[batch * CC + rowL + 16 * j], v);
    }
  }

  // ---------------- global barrier: relaxed counter, no cache maintenance.
  // __syncthreads drains vmcnt(0), so this block's S/r atomics are globally
  // acknowledged (memory-side, sc1) before the counter bump is issued.
  __syncthreads();
  if (t == 0) {
    __hip_atomic_fetch_add(ctr, 1u, __ATOMIC_RELAXED,
                           __HIP_MEMORY_SCOPE_AGENT);
    while (__hip_atomic_load(ctr, __ATOMIC_RELAXED,
                             __HIP_MEMORY_SCOPE_AGENT) < (unsigned)NBLK) {
      __builtin_amdgcn_s_sleep(2);
    }
  }
  __syncthreads();

  // ---------------- phase 2: redundant tiny algebra -> Wt, bl in LDS
  {
    Alg& a = sm.u.alg;
    const float* Sb = Sf + (size_t)batch * CC * CC;
    for (int idx = t; idx < CC * CC; idx += 256)
      a.S[idx >> 6][idx & 63] = __hip_atomic_load(
          &Sb[idx], __ATOMIC_RELAXED, __HIP_MEMORY_SCOPE_AGENT);
    for (int idx = t; idx < CI * CC; idx += 256) {
      int c = idx >> 6, j = idx & 63;
      a.Gt[j][c] = gw[idx];
    }
    if (t < CC)
      a.r[t] = __hip_atomic_load(&rf[batch * CC + t], __ATOMIC_RELAXED,
                                 __HIP_MEMORY_SCOPE_AGENT);
    __syncthreads();

    if (t < CI) {
      float s = 0.f;
      for (int i = 0; i < CC; ++i) s += gw[t * CC + i] * a.r[i];
      a.u[t] = s;
    } else if (t < 2 * CI) {
      const int k = t - CI;
      float s = 0.f;
      for (int i = 0; i < CC; ++i) s += pw[k * CC + i] * a.r[i];
      a.v[k] = s;
    }
    // A[k][j] = sum_i pw[k][i] S[i][j]
    for (int o = t; o < CI * CC; o += 256) {
      const int k = o >> 6, j = o & 63;
      float s = 0.f;
      for (int i = 0; i < CC; ++i) s += pw[k * CC + i] * a.S[i][j];
      a.A[k][j] = s;
    }
    __syncthreads();

    // M[k][c] = sum_j A[k][j] Gt[j][c] + v[k] gb[c] + pb[k] u[c] + N pb[k] gb[c]
    for (int o = t; o < CI * CI; o += 256) {
      const int k = o >> 5, c = o & 31;
      float s = 0.f;
      for (int j = 0; j < CC; ++j) s += a.A[k][j] * a.Gt[j][c];
      s += a.v[k] * gb[c] + pb[k] * a.u[c] + (float)NPIX * pb[k] * gb[c];
      a.M[k][c] = s;
    }
    __syncthreads();

    // T1[c][j] = sum_k M[k][c] tw[k][j];  t2[c] = sum_k M[k][c] tb[k]
    for (int o = t; o < CI * CC; o += 256) {
      const int c = o >> 6, j = o & 63;
      float s = 0.f;
      for (int k = 0; k < CI; ++k) s += a.M[k][c] * tw[k * CC + j];
      a.T1[c][j] = s;
    }
    if (t < CI) {
      float s = 0.f;
      for (int k = 0; k < CI; ++k) s += a.M[k][t] * tb[k];
      a.t2[t] = s;
    }
    __syncthreads();

    const float invN = 1.0f / (float)NPIX;
    // Wt[j][oc] = invN * sum_c rw[oc][c] T1[c][j]   (transposed for apply)
    for (int o = t; o < CC * CC; o += 256) {
      const int oc = o >> 6, j = o & 63;
      float s = 0.f;
      for (int c = 0; c < CI; ++c) s += rw[oc * CI + c] * a.T1[c][j];
      sm.Wt[j][oc] = s * invN;
    }
    if (t < CC) {
      float s = 0.f;
      for (int c = 0; c < CI; ++c) s += rw[t * CI + c] * a.t2[c];
      sm.bl[t] = s * invN + rb[t];
    }
  }
  __syncthreads();

  // ---------------- phase 3: Z = X + W_b X + b_b for this block's tile
  {
    const int n0 = chk * TN;
    const float* __restrict__ X = x + (size_t)batch * CC * NPIX;
    float* __restrict__ Z = z + (size_t)batch * CC * NPIX;

    for (int idx = t; idx < CC * TN; idx += 256) {
      const int k = idx >> 7, n = idx & (TN - 1);
      sm.u.xt[k][n] = X[(size_t)k * NPIX + n0 + n];
    }
    __syncthreads();

    const int c0 = (t >> 5) * 8;
    const int m0 = (t & 31) * 4;
    float acc[8][4] = {};
#pragma unroll 4
    for (int k = 0; k < CC; ++k) {
      const float4 xv = *reinterpret_cast<const float4*>(&sm.u.xt[k][m0]);
      const float4 w0 = *reinterpret_cast<const float4*>(&sm.Wt[k][c0]);
      const float4 w1 = *reinterpret_cast<const float4*>(&sm.Wt[k][c0 + 4]);
      const float xa[4] = {xv.x, xv.y, xv.z, xv.w};
      const float wa[8] = {w0.x, w0.y, w0.z, w0.w, w1.x, w1.y, w1.z, w1.w};
#pragma unroll
      for (int cc = 0; cc < 8; ++cc)
#pragma unroll
        for (int nn = 0; nn < 4; ++nn) acc[cc][nn] += wa[cc] * xa[nn];
    }

#pragma unroll
    for (int cc = 0; cc < 8; ++cc) {
      const int c = c0 + cc;
      const float4 xr = *reinterpret_cast<const float4*>(&sm.u.xt[c][m0]);
      const float bb2 = sm.bl[c];
      float4 o;
      o.x = acc[cc][0] + xr.x + bb2;
      o.y = acc[cc][1] + xr.y + bb2;
      o.z = acc[cc][2] + xr.z + bb2;
      o.w = acc[cc][3] + xr.w + bb2;
      *reinterpret_cast<float4*>(&Z[(size_t)c * NPIX + n0 + m0]) = o;
    }
  }
}

extern "C" void kernel_launch(void* const* d_in, const int* in_sizes, int n_in,
                              void* d_out, int out_size, void* d_ws,
                              size_t ws_size, hipStream_t stream) {
  (void)in_sizes; (void)n_in; (void)out_size; (void)ws_size;
  const float* x  = (const float*)d_in[0];
  const float* tw = (const float*)d_in[1];
  const float* tb = (const float*)d_in[2];
  const float* pw = (const float*)d_in[3];
  const float* pb = (const float*)d_in[4];
  const float* gw = (const float*)d_in[5];
  const float* gb = (const float*)d_in[6];
  const float* rw = (const float*)d_in[7];
  const float* rb = (const float*)d_in[8];
  float* z = (float*)d_out;

  float* Sf = (float*)d_ws;                       // BB*4096
  float* rf = Sf + (size_t)BB * CC * CC;          // BB*64
  unsigned int* ctr = (unsigned int*)(rf + BB * CC);

  const size_t zero_bytes = ((size_t)BB * (CC * CC + CC)) * sizeof(float) + 16;
  hipMemsetAsync(d_ws, 0, zero_bytes, stream);

  hipLaunchKernelGGL(fused_nonlocal, dim3(NBLK), dim3(256), 0, stream,
                     x, tw, tb, pw, pb, gw, gb, rw, rb, z, Sf, rf, ctr);
}